// Round 1
// 65.234 us; speedup vs baseline: 1.0459x; 1.0459x over previous
//
#include <hip/hip_runtime.h>

// loss = sum_{i: yt=1, j: yt=0} max(0, 1 - yp_i + yp_j) / (n_pos * n_neg), N=16384.
//
// Round 5: kill the single-address atomic tail.
//   R4 evidence: auc_kernel absent from rocprof top-5 (all fills @39.2us) =>
//   kernel < 39us; dur_us 68.2 ~= 39.3us poison fill (harness fixed cost) +
//   ~29us kernel. Phase arithmetic says compute is only ~5-6us; the missing
//   ~23us is the epilogue: 256 device-scope atomicAdds to ONE address,
//   arriving in a burst (uniform work, 1 block/CU) -> cross-XCD cacheline
//   serialization ~100-200ns each ~= 25us tail.
//   Fix: each block plain-stores its scaled partial to a line-padded d_ws
//   slot; a second 1-block kernel sums 256 floats and plain-stores out.
//   No atomics, no dependence on poison values, graph-capture safe.
//   Everything else byte-identical to R4 to isolate the change.
//
//   - 256 blocks x 512 threads, 128KB dynamic LDS (1 block/CU, 8 waves).
//   - Each block loads the full input (coalesced float4/int4, L2-hot) into
//     registers, then DETERMINISTICALLY compacts pos->cs (as 1-yp), neg->qs
//     into LDS: wave totals via shuffle-reduce + fixed-order prefix, then
//     in-order per-wave ballot rounds with running offsets. Identical
//     permutation in every block -> blocks may partition the row space.
//   - Pair phase, balanced: block b owns compacted rows [b*rpb,(b+1)*rpb),
//     rpb=ceil(npos/256). Each thread holds 16 q's in registers (lane-strided
//     float4 LDS reads, even bank spread); rows broadcast 4-at-a-time from
//     LDS; 3 VALU ops per pair -> ~2.6us aggregate at 201M pairs.

#define N_TOTAL 16384
#define BLOCK 512
#define GRID 256
#define NWAVES (BLOCK / 64)
#define K_CHUNKS 8  // 8 x float4 per thread = 32 elems; 512*32 = 16384
#define SMEM_BYTES (2 * N_TOTAL * 4)
#define WS_STRIDE 16  // floats: 64B per block partial -> no cross-XCD line sharing

__global__ void __launch_bounds__(BLOCK) auc_kernel(
    const int* __restrict__ yt, const float* __restrict__ yp,
    float* __restrict__ ws) {
  extern __shared__ float smem[];
  float* cs = smem;            // [16384] compacted 1-yp (pos) + sentinel pad
  float* qs = smem + N_TOTAL;  // [16384] compacted yp (neg) + sentinel pad
  __shared__ int waveTotS[NWAVES];
  __shared__ float wsum[NWAVES];

  const int tid = threadIdx.x;
  const int lane = tid & 63;
  const int wid = tid >> 6;
  const int b = blockIdx.x;

  // ---- pass 1: coalesced vector loads; values + pos-mask kept in registers
  float4 v[K_CHUNKS];
  unsigned mask = 0;
  int pc = 0;
#pragma unroll
  for (int k = 0; k < K_CHUNKS; ++k) {
    const int e = k * (BLOCK * 4) + tid * 4;
    const int4 t4 = *(const int4*)(yt + e);
    v[k] = *(const float4*)(yp + e);
    const unsigned m = (t4.x == 1 ? 1u : 0u) | (t4.y == 1 ? 2u : 0u) |
                       (t4.z == 1 ? 4u : 0u) | (t4.w == 1 ? 8u : 0u);
    mask |= m << (k * 4);
    pc += __popc(m);
  }

  // ---- wave pos-totals (butterfly), fixed-order prefix over waves
  int wtot = pc;
#pragma unroll
  for (int off = 1; off < 64; off <<= 1) wtot += __shfl_xor(wtot, off, 64);
  if (lane == 0) waveTotS[wid] = wtot;
  __syncthreads();
  int npos = 0, posBaseW = 0;
#pragma unroll
  for (int w = 0; w < NWAVES; ++w) {
    const int c = waveTotS[w];
    if (w < wid) posBaseW += c;
    npos += c;
  }
  const int nneg = N_TOTAL - npos;
  const int negBaseW = wid * 2048 - posBaseW;  // each wave owns 2048 elems

  // ---- pass 2: in-order per-wave ballot compaction (deterministic; stores
  //      are rank-consecutive -> conflict-free; no LDS atomics)
  {
    int runP = 0, runN = 0;
    const unsigned long long lt = (1ull << lane) - 1ull;
#pragma unroll
    for (int k = 0; k < K_CHUNKS; ++k) {
#pragma unroll
      for (int c = 0; c < 4; ++c) {
        const float val = (c == 0) ? v[k].x
                        : (c == 1) ? v[k].y
                        : (c == 2) ? v[k].z : v[k].w;
        const bool isPos = (mask >> (k * 4 + c)) & 1u;
        const unsigned long long bal = __ballot(isPos);
        const int rankP = __popcll(bal & lt);
        if (isPos) cs[posBaseW + runP + rankP] = 1.0f - val;
        else       qs[negBaseW + runN + (lane - rankP)] = val;
        const int cnt = __popcll(bal);
        runP += cnt;
        runN += 64 - cnt;
      }
    }
  }

  // ---- sentinel pads (disjoint from pass-2 writes; barrier before reads)
  const int rpb = (npos + GRID - 1) / GRID;  // rows per block, block-uniform
  const int rowsPad = rpb * GRID;            // <= 16384
  for (int i = npos + tid; i < rowsPad; i += BLOCK) cs[i] = -3e30f;
  const int padded = (nneg + 3) & ~3;        // <= 16384
  for (int i = nneg + tid; i < padded; i += BLOCK) qs[i] = -1e30f;
  __syncthreads();

  // ---- pair phase: rows [b*rpb, (b+1)*rpb), 16 q's/thread in registers
  const int rowBase = b * rpb;
  const int nCh = (rpb + 3) >> 2;
  float acc[16];
#pragma unroll
  for (int i = 0; i < 16; ++i) acc[i] = 0.f;

  for (int jt = 0; jt < padded; jt += 8192) {
    if (jt + tid * 4 >= padded) break;  // tail threads idle (wave-coherent)
    float qreg[16];
#pragma unroll
    for (int w = 0; w < 4; ++w) {
      const int j0 = jt + w * 2048 + tid * 4;
      if (j0 < padded) {
        const float4 q4 = *(const float4*)(qs + j0);
        qreg[w * 4 + 0] = q4.x; qreg[w * 4 + 1] = q4.y;
        qreg[w * 4 + 2] = q4.z; qreg[w * 4 + 3] = q4.w;
      } else {
        qreg[w * 4 + 0] = qreg[w * 4 + 1] = -1e30f;
        qreg[w * 4 + 2] = qreg[w * 4 + 3] = -1e30f;
      }
    }
    for (int ch = 0; ch < nCh; ++ch) {
      const int r0 = ch * 4;
#pragma unroll
      for (int r = 0; r < 4; ++r) {
        float cv = cs[rowBase + r0 + r];        // wave-uniform -> broadcast
        cv = (r0 + r < rpb) ? cv : -3e30f;      // tail rows -> sentinel
#pragma unroll
        for (int q = 0; q < 16; ++q) acc[q] += fmaxf(0.f, cv + qreg[q]);
      }
    }
  }

  // ---- reduce: thread -> wave -> block -> ONE PLAIN STORE per block.
  //      (R4 used atomicAdd(out,...): 256 same-address device-scope atomics
  //      in a burst = cross-XCD serialization tail. Plain stores to
  //      line-padded ws slots are contention-free; kernel boundary flushes
  //      L2 so reduce_kernel sees all partials.)
  float s = 0.f;
#pragma unroll
  for (int i = 0; i < 16; ++i) s += acc[i];
#pragma unroll
  for (int off = 32; off > 0; off >>= 1) s += __shfl_down(s, off, 64);
  if (lane == 0) wsum[wid] = s;
  __syncthreads();
  if (tid == 0) {
    float bs = 0.f;
#pragma unroll
    for (int w = 0; w < NWAVES; ++w) bs += wsum[w];
    ws[(size_t)b * WS_STRIDE] = bs / ((float)npos * (float)nneg);
  }
}

__global__ void __launch_bounds__(256) reduce_kernel(
    const float* __restrict__ ws, float* __restrict__ out) {
  __shared__ float wsum[4];
  const int tid = threadIdx.x;
  const int lane = tid & 63;
  const int wid = tid >> 6;
  float s = ws[(size_t)tid * WS_STRIDE];  // 256 partials, one per block
#pragma unroll
  for (int off = 32; off > 0; off >>= 1) s += __shfl_down(s, off, 64);
  if (lane == 0) wsum[wid] = s;
  __syncthreads();
  if (tid == 0) out[0] = wsum[0] + wsum[1] + wsum[2] + wsum[3];  // plain store
}

extern "C" void kernel_launch(void* const* d_in, const int* in_sizes, int n_in,
                              void* d_out, int out_size, void* d_ws,
                              size_t ws_size, hipStream_t stream) {
  const int* yt = (const int*)d_in[0];      // y_true, int32, 16384
  const float* yp = (const float*)d_in[1];  // y_pred, float32, 16384
  float* out = (float*)d_out;
  float* ws = (float*)d_ws;                 // needs 256*16*4 = 16KB << ws_size

  // Opt in to 128KB dynamic LDS (host-side, capture-safe; worked in R3/R4).
  hipFuncSetAttribute((const void*)auc_kernel,
                      hipFuncAttributeMaxDynamicSharedMemorySize, SMEM_BYTES);

  auc_kernel<<<GRID, BLOCK, SMEM_BYTES, stream>>>(yt, yp, ws);
  reduce_kernel<<<1, 256, 0, stream>>>(ws, out);
}